// Round 6
// baseline (6073.521 us; speedup 1.0000x reference)
//
#include <hip/hip_runtime.h>

#define NUMS   128
#define NVARS  16
#define BATCH  8192
#define ITERS  15

// d_out element offsets (return order: cv, cp, cr, acc_fixed, acc_primal, primal_stack, fixed_stack)
#define OUT_ACCF (3*BATCH*NVARS)           // 393216
#define OUT_ACCP (OUT_ACCF + BATCH)        // 401408
#define OUT_PST  (OUT_ACCP + BATCH)        // 409600
#define OUT_FST  (OUT_PST + ITERS*BATCH)   // 532480

// ---------------------------------------------------------------------------
// prep: AtA = 2(P^T P + Pd^T Pd + Pdd^T Pdd); cost_mat = [[I+AtA, Aeq^T],[Aeq,0]];
// M = inv(cost_mat) via f64 Gauss-Jordan. ws: [0,324) M row-major f32,
// [324,596) AtA padded [16][17] f32.
// ---------------------------------------------------------------------------
__global__ void prep_kernel(const float* __restrict__ P, const float* __restrict__ Pd,
                            const float* __restrict__ Pdd, float* __restrict__ ws)
{
    __shared__ double GA[18][36];
    __shared__ float  ata[16][16];
    __shared__ double piv_s;
    const int t = threadIdx.x;

    if (t < 256) {
        int j = t >> 4, k = t & 15;
        float s = 0.f;
        for (int i = 0; i < NUMS; ++i)
            s += P[i*16+j]*P[i*16+k] + Pd[i*16+j]*Pd[i*16+k] + Pdd[i*16+j]*Pdd[i*16+k];
        ata[j][k] = 2.f * s;
    }
    __syncthreads();

    const int gi = t / 36, gj = t % 36;   // blockDim = 648
    {
        double v;
        if (gj < 18) {
            if (gi < 16 && gj < 16)      v = (gi == gj ? 1.0 : 0.0) + (double)ata[gi][gj];
            else if (gi < 16)            v = (gj == 16) ? (double)P[gi] : (double)Pd[gi];
            else if (gj < 16)            v = (gi == 16) ? (double)P[gj] : (double)Pd[gj];
            else                         v = 0.0;
        } else {
            v = ((gj - 18) == gi) ? 1.0 : 0.0;
        }
        GA[gi][gj] = v;
    }
    __syncthreads();

    for (int k = 0; k < 18; ++k) {
        if (t == 0) piv_s = GA[k][k];
        __syncthreads();
        if (gi == k) GA[gi][gj] /= piv_s;
        __syncthreads();
        double f  = GA[gi][k];
        double rk = GA[k][gj];
        __syncthreads();
        if (gi != k) GA[gi][gj] -= f * rk;
        __syncthreads();
    }

    if (gj >= 18) ws[gi*18 + (gj - 18)] = (float)GA[gi][gj];
    if (t < 256)  ws[324 + (t >> 4)*17 + (t & 15)] = ata[t >> 4][t & 15];
    if (t >= 256 && t < 272) ws[324 + (t - 256)*17 + 16] = 0.f;
}

// ---------------------------------------------------------------------------
// main solver: block = 192 threads = 12 groups of 16 lanes = 4 rows x 3 channels.
// State is DISTRIBUTED: lane l of a group owns component l of c, L, cq, pj.
// NO __launch_bounds__: (192,2) made the backend cap VGPRs at the 128
// occupancy step (9 waves/CU target -> 512/3=170 -> rounds to 128) while
// peak live (state + pipelined ds_read/shfl staging) exceeds it -> every
// round so far spilled (R1 9.1GB, R4 17.6GB, R5 8.1GB scratch traffic).
// Uncapped (512 max, m08: no spill through 450) the allocator takes ~160-220.
// ---------------------------------------------------------------------------
__global__ void solve_kernel(
    const float* __restrict__ P,    const float* __restrict__ Pd,   const float* __restrict__ Pdd,
    const float* __restrict__ lamv, const float* __restrict__ lamp, const float* __restrict__ lamr,
    const float* __restrict__ cinv, const float* __restrict__ cinp, const float* __restrict__ cinr,
    const float* __restrict__ beqv, const float* __restrict__ beqp, const float* __restrict__ beqr,
    const float* __restrict__ c0v,  const float* __restrict__ c0p,  const float* __restrict__ c0r,
    float* __restrict__ out, const float* __restrict__ ws)
{
    __shared__ __align__(16) float Pt[3][16][128];   // transposed: Pt[m][j][i]
    __shared__ float Ml[16][19];                     // M rows 0..15, cols 0..17 (pad 19)
    __shared__ float ata[16][17];
    __shared__ float res_st[ITERS][12];
    __shared__ float fix_st[ITERS][12];

    // ---- stage constants ----
#pragma unroll
    for (int m = 0; m < 3; ++m) {
        const float* src = (m == 0) ? P : (m == 1) ? Pd : Pdd;
        for (int f = threadIdx.x; f < 2048; f += 192) {
            int j = f >> 7, i = f & 127;
            Pt[m][j][i] = src[i*16 + j];
        }
    }
    for (int f = threadIdx.x; f < 288; f += 192) Ml[f / 18][f % 18] = ws[f];
    for (int f = threadIdx.x; f < 272; f += 192) ((float*)ata)[f] = ws[324 + f];
    __syncthreads();

    const int g  = threadIdx.x >> 4;   // group 0..11
    const int l  = threadIdx.x & 15;   // lane-in-group
    const int rl = g / 3;              // local row 0..3
    const int ch = g - rl * 3;         // channel 0..2
    const int row = blockIdx.x * 4 + rl;

    const float* lam_p = (ch == 0) ? lamv : (ch == 1) ? lamp : lamr;
    const float* cin_p = (ch == 0) ? cinv : (ch == 1) ? cinp : cinr;
    const float* beq_p = (ch == 0) ? beqv : (ch == 1) ? beqp : beqr;
    const float* c0_p  = (ch == 0) ? c0v  : (ch == 1) ? c0p  : c0r;

    // bounds per (ch, m)
    float bmax[3], bmin[3];
    bmax[0] = (ch == 0) ? 20.f : (ch == 1) ? 0.2f  : 0.25f;
    bmin[0] = (ch == 0) ? 12.f : (ch == 1) ? -0.2f : -0.25f;
    bmax[1] = (ch == 0) ? 3.f  : 0.25f;
    bmin[1] = (ch == 0) ? -3.f : -0.25f;
    bmax[2] = (ch == 0) ? 3.f  : 0.15f;
    bmin[2] = (ch == 0) ? -3.f : -0.15f;

    // ---- distributed per-unit state: lane l owns component l ----
    float c_l  = c0_p[row * 16 + l];
    float L_l  = lam_p[row * 16 + l] + cin_p[row * 16 + l];
    float pj_l, cq_l;
    const float beq0 = beq_p[row * 2];
    const float beq1 = beq_p[row * 2 + 1];
    float uo[3][8];                    // lane's 8 constraint rows per derivative order

    // ---- init pass: uo, pj0, cq0 from c0 ----
    {
        float cb[16];
#pragma unroll
        for (int k = 0; k < 16; ++k) cb[k] = __shfl(c_l, k, 16);

        float cqd = 0.f;
#pragma unroll
        for (int k = 0; k < 16; ++k) cqd += ata[l][k] * cb[k];
        cq_l = cqd;

        float pjp[16];
#pragma unroll
        for (int j = 0; j < 16; ++j) pjp[j] = 0.f;
#pragma unroll
        for (int m = 0; m < 3; ++m) {
            float un[8], h[8];
#pragma unroll
            for (int k = 0; k < 8; ++k) un[k] = 0.f;
#pragma unroll
            for (int j = 0; j < 16; ++j) {
                float4 p0 = *(const float4*)&Pt[m][j][4*l];
                float4 p1 = *(const float4*)&Pt[m][j][64 + 4*l];
                un[0] += cb[j]*p0.x; un[1] += cb[j]*p0.y; un[2] += cb[j]*p0.z; un[3] += cb[j]*p0.w;
                un[4] += cb[j]*p1.x; un[5] += cb[j]*p1.y; un[6] += cb[j]*p1.z; un[7] += cb[j]*p1.w;
            }
#pragma unroll
            for (int k = 0; k < 8; ++k) {
                float x = un[k] - bmax[m];
                float rvp = fmaxf(x, 0.f);
                float y = un[k] - bmin[m];
                float rvm = fmaxf(-y, 0.f);
                h[k] = rvp - rvm;
                uo[m][k] = un[k];
            }
#pragma unroll
            for (int j = 0; j < 16; ++j) {
                float4 p0 = *(const float4*)&Pt[m][j][4*l];
                float4 p1 = *(const float4*)&Pt[m][j][64 + 4*l];
                pjp[j] += h[0]*p0.x + h[1]*p0.y + h[2]*p0.z + h[3]*p0.w
                        + h[4]*p1.x + h[5]*p1.y + h[6]*p1.z + h[7]*p1.w;
            }
        }
#pragma unroll
        for (int s = 1; s < 16; s <<= 1) {
#pragma unroll
            for (int j = 0; j < 16; ++j) pjp[j] += __shfl_xor(pjp[j], s, 16);
        }
        float pjl = pjp[0];
#pragma unroll
        for (int k = 1; k < 16; ++k) pjl = (l == k) ? pjp[k] : pjl;
        pj_l = pjl;
    }

    // ---- 15 ADMM iterations ----
    for (int t = 0; t < ITERS; ++t) {
        // KKT solve: rhs_k = L_k + cq_k - pj_k (distributed); lane l owns M row l
        float r_l = L_l + cq_l - pj_l;
        float sj = Ml[l][16] * beq0 + Ml[l][17] * beq1;
#pragma unroll
        for (int k = 0; k < 16; ++k) sj += Ml[l][k] * __shfl(r_l, k, 16);

        float d = sj - c_l;
        float cdel2 = d * d;           // per-lane partial of ||c_new - c_old||^2
        c_l = sj;

        // broadcast new c
        float cb[16];
#pragma unroll
        for (int k = 0; k < 16; ++k) cb[k] = __shfl(c_l, k, 16);

        // cq for next solve: lane l computes (AtA c)_l
        float cqd = 0.f;
#pragma unroll
        for (int k = 0; k < 16; ++k) cqd += ata[l][k] * cb[k];
        cq_l = cqd;

        // projection passes
        float res2 = 0.f, ds2 = 0.f;
        float pjp[16];
#pragma unroll
        for (int j = 0; j < 16; ++j) pjp[j] = 0.f;

#pragma unroll
        for (int m = 0; m < 3; ++m) {
            float un[8], h[8];
#pragma unroll
            for (int k = 0; k < 8; ++k) un[k] = 0.f;
#pragma unroll
            for (int j = 0; j < 16; ++j) {
                float4 p0 = *(const float4*)&Pt[m][j][4*l];
                float4 p1 = *(const float4*)&Pt[m][j][64 + 4*l];
                un[0] += cb[j]*p0.x; un[1] += cb[j]*p0.y; un[2] += cb[j]*p0.z; un[3] += cb[j]*p0.w;
                un[4] += cb[j]*p1.x; un[5] += cb[j]*p1.y; un[6] += cb[j]*p1.z; un[7] += cb[j]*p1.w;
            }
#pragma unroll
            for (int k = 0; k < 8; ++k) {
                float x   = un[k] - bmax[m];
                float rvp = fmaxf(x, 0.f);        // relu(Ax - bmax)
                float spn = rvp - x;              // relu(bmax - Ax)  (new s+)
                float y   = un[k] - bmin[m];
                float smn = fmaxf(y, 0.f);        // relu(Ax - bmin)  (new s-)
                float rvm = smn - y;              // relu(bmin - Ax)
                res2 += rvp * rvp;
                res2 += rvm * rvm;
                h[k] = rvp - rvm;
                float xo  = uo[m][k] - bmax[m];
                float spo = fmaxf(-xo, 0.f);      // old s+
                float yo  = uo[m][k] - bmin[m];
                float smo = fmaxf(yo, 0.f);       // old s-
                float e1 = spn - spo;
                float e2 = smn - smo;
                ds2 += e1 * e1;
                ds2 += e2 * e2;
                uo[m][k] = un[k];
            }
#pragma unroll
            for (int j = 0; j < 16; ++j) {
                float4 p0 = *(const float4*)&Pt[m][j][4*l];
                float4 p1 = *(const float4*)&Pt[m][j][64 + 4*l];
                pjp[j] += h[0]*p0.x + h[1]*p0.y + h[2]*p0.z + h[3]*p0.w
                        + h[4]*p1.x + h[5]*p1.y + h[6]*p1.z + h[7]*p1.w;
            }
        }

        // butterfly reduce: pjp[16] + res2 + ds2 + cdel2 across the 16 lanes
#pragma unroll
        for (int s = 1; s < 16; s <<= 1) {
#pragma unroll
            for (int j = 0; j < 16; ++j) pjp[j] += __shfl_xor(pjp[j], s, 16);
            res2  += __shfl_xor(res2,  s, 16);
            ds2   += __shfl_xor(ds2,   s, 16);
            cdel2 += __shfl_xor(cdel2, s, 16);
        }

        // lane l extracts its component (static cndmask chain, no scratch)
        float pjl = pjp[0];
#pragma unroll
        for (int k = 1; k < 16; ++k) pjl = (l == k) ? pjp[k] : pjl;

        // ||lamda_new - lamda_old||^2 = sum pj^2 (replicated: all lanes have full pjp)
        float ln2 = 0.f;
#pragma unroll
        for (int k = 0; k < 16; ++k) ln2 += pjp[k] * pjp[k];

        L_l -= pjl;
        pj_l = pjl;

        if (l == 0) {
            res_st[t][g] = sqrtf(res2);
            fix_st[t][g] = sqrtf(ln2) + sqrtf(ds2) + sqrtf(cdel2);
        }
    }

    // ---- outputs ----
    out[ch * (BATCH * NVARS) + row * 16 + l] = c_l;   // lane l owns c[l]

    __syncthreads();
    const int t2 = threadIdx.x;
    if (t2 < 60) {
        int it = t2 % 15, r2 = t2 / 15, gb = r2 * 3;
        out[OUT_PST + it * BATCH + blockIdx.x * 4 + r2] =
            res_st[it][gb] + res_st[it][gb + 1] + res_st[it][gb + 2];
    } else if (t2 < 120) {
        int t3 = t2 - 60;
        int it = t3 % 15, r2 = t3 / 15, gb = r2 * 3;
        out[OUT_FST + it * BATCH + blockIdx.x * 4 + r2] =
            fix_st[it][gb] + fix_st[it][gb + 1] + fix_st[it][gb + 2];
    } else if (t2 < 124) {
        int r2 = t2 - 120, gb = r2 * 3;
        float s = 0.f;
        for (int it = 0; it < ITERS; ++it)
            s += fix_st[it][gb] + fix_st[it][gb + 1] + fix_st[it][gb + 2];
        out[OUT_ACCF + blockIdx.x * 4 + r2] = s * (1.f / 15.f);
    } else if (t2 < 128) {
        int r2 = t2 - 124, gb = r2 * 3;
        float s = 0.f;
        for (int it = 0; it < ITERS; ++it)
            s += res_st[it][gb] + res_st[it][gb + 1] + res_st[it][gb + 2];
        out[OUT_ACCP + blockIdx.x * 4 + r2] = s * (1.f / 15.f);
    }
}

extern "C" void kernel_launch(void* const* d_in, const int* in_sizes, int n_in,
                              void* d_out, int out_size, void* d_ws, size_t ws_size,
                              hipStream_t stream)
{
    const float* P    = (const float*)d_in[0];
    const float* Pdm  = (const float*)d_in[1];
    const float* Pddm = (const float*)d_in[2];
    const float* lamv = (const float*)d_in[3];
    const float* lamp = (const float*)d_in[4];
    const float* lamr = (const float*)d_in[5];
    const float* cinv = (const float*)d_in[6];
    const float* cinp = (const float*)d_in[7];
    const float* cinr = (const float*)d_in[8];
    const float* beqv = (const float*)d_in[9];
    const float* beqp = (const float*)d_in[10];
    const float* beqr = (const float*)d_in[11];
    const float* c0v  = (const float*)d_in[12];
    const float* c0p  = (const float*)d_in[13];
    const float* c0r  = (const float*)d_in[14];
    float* ws = (float*)d_ws;

    prep_kernel<<<1, 648, 0, stream>>>(P, Pdm, Pddm, ws);
    solve_kernel<<<2048, 192, 0, stream>>>(P, Pdm, Pddm,
        lamv, lamp, lamr, cinv, cinp, cinr,
        beqv, beqp, beqr, c0v, c0p, c0r,
        (float*)d_out, ws);
}

// Round 8
// 2643.693 us; speedup vs baseline: 2.2974x; 2.2974x over previous
//
#include <hip/hip_runtime.h>

#define NUMS   128
#define NVARS  16
#define BATCH  8192
#define ITERS  15

// d_out element offsets (return order: cv, cp, cr, acc_fixed, acc_primal, primal_stack, fixed_stack)
#define OUT_ACCF (3*BATCH*NVARS)           // 393216
#define OUT_ACCP (OUT_ACCF + BATCH)        // 401408
#define OUT_PST  (OUT_ACCP + BATCH)        // 409600
#define OUT_FST  (OUT_PST + ITERS*BATCH)   // 532480

// ---------------------------------------------------------------------------
// prep: AtA = 2(P^T P + Pd^T Pd + Pdd^T Pdd); cost_mat = [[I+AtA, Aeq^T],[Aeq,0]];
// M = inv(cost_mat) via f64 Gauss-Jordan. ws: [0,324) M row-major f32,
// [324,596) AtA padded [16][17] f32.
// ---------------------------------------------------------------------------
__global__ void prep_kernel(const float* __restrict__ P, const float* __restrict__ Pd,
                            const float* __restrict__ Pdd, float* __restrict__ ws)
{
    __shared__ double GA[18][36];
    __shared__ float  ata[16][16];
    __shared__ double piv_s;
    const int t = threadIdx.x;

    if (t < 256) {
        int j = t >> 4, k = t & 15;
        float s = 0.f;
        for (int i = 0; i < NUMS; ++i)
            s += P[i*16+j]*P[i*16+k] + Pd[i*16+j]*Pd[i*16+k] + Pdd[i*16+j]*Pdd[i*16+k];
        ata[j][k] = 2.f * s;
    }
    __syncthreads();

    const int gi = t / 36, gj = t % 36;   // blockDim = 648
    {
        double v;
        if (gj < 18) {
            if (gi < 16 && gj < 16)      v = (gi == gj ? 1.0 : 0.0) + (double)ata[gi][gj];
            else if (gi < 16)            v = (gj == 16) ? (double)P[gi] : (double)Pd[gi];
            else if (gj < 16)            v = (gi == 16) ? (double)P[gj] : (double)Pd[gj];
            else                         v = 0.0;
        } else {
            v = ((gj - 18) == gi) ? 1.0 : 0.0;
        }
        GA[gi][gj] = v;
    }
    __syncthreads();

    for (int k = 0; k < 18; ++k) {
        if (t == 0) piv_s = GA[k][k];
        __syncthreads();
        if (gi == k) GA[gi][gj] /= piv_s;
        __syncthreads();
        double f  = GA[gi][k];
        double rk = GA[k][gj];
        __syncthreads();
        if (gi != k) GA[gi][gj] -= f * rk;
        __syncthreads();
    }

    if (gj >= 18) ws[gi*18 + (gj - 18)] = (float)GA[gi][gj];
    if (t < 256)  ws[324 + (t >> 4)*17 + (t & 15)] = ata[t >> 4][t & 15];
    if (t >= 256 && t < 272) ws[324 + (t - 256)*17 + 16] = 0.f;
}

// ---------------------------------------------------------------------------
// main solver: block = 192 threads = 12 groups of 16 lanes = 4 rows x 3 channels.
// State is DISTRIBUTED: lane l of a group owns component l of c, L, cq, pj.
//
// __launch_bounds__(192, 1): min 1 wave/EU -> VGPR cap 512. Evidence across
// R1/R4/R5/R6: the allocator always honors the occupancy-derived VGPR cap
// (none=64, (192,4)=64, (192,2)=128) and spills the ~130-reg live set to
// scratch; dur tracked spill bytes exactly (8-17.6 GB phantom HBM traffic).
// Cap 512 (m08: no spill through 450) lets the allocator take ~160-220.
// ---------------------------------------------------------------------------
__launch_bounds__(192, 1)
__global__ void solve_kernel(
    const float* __restrict__ P,    const float* __restrict__ Pd,   const float* __restrict__ Pdd,
    const float* __restrict__ lamv, const float* __restrict__ lamp, const float* __restrict__ lamr,
    const float* __restrict__ cinv, const float* __restrict__ cinp, const float* __restrict__ cinr,
    const float* __restrict__ beqv, const float* __restrict__ beqp, const float* __restrict__ beqr,
    const float* __restrict__ c0v,  const float* __restrict__ c0p,  const float* __restrict__ c0r,
    float* __restrict__ out, const float* __restrict__ ws)
{
    __shared__ __align__(16) float Pt[3][16][128];   // transposed: Pt[m][j][i]
    __shared__ float Ml[16][19];                     // M rows 0..15, cols 0..17 (pad 19)
    __shared__ float ata[16][17];
    __shared__ float res_st[ITERS][12];
    __shared__ float fix_st[ITERS][12];

    // ---- stage constants ----
#pragma unroll
    for (int m = 0; m < 3; ++m) {
        const float* src = (m == 0) ? P : (m == 1) ? Pd : Pdd;
        for (int f = threadIdx.x; f < 2048; f += 192) {
            int j = f >> 7, i = f & 127;
            Pt[m][j][i] = src[i*16 + j];
        }
    }
    for (int f = threadIdx.x; f < 288; f += 192) Ml[f / 18][f % 18] = ws[f];
    for (int f = threadIdx.x; f < 272; f += 192) ((float*)ata)[f] = ws[324 + f];
    __syncthreads();

    const int g  = threadIdx.x >> 4;   // group 0..11
    const int l  = threadIdx.x & 15;   // lane-in-group
    const int rl = g / 3;              // local row 0..3
    const int ch = g - rl * 3;         // channel 0..2
    const int row = blockIdx.x * 4 + rl;

    const float* lam_p = (ch == 0) ? lamv : (ch == 1) ? lamp : lamr;
    const float* cin_p = (ch == 0) ? cinv : (ch == 1) ? cinp : cinr;
    const float* beq_p = (ch == 0) ? beqv : (ch == 1) ? beqp : beqr;
    const float* c0_p  = (ch == 0) ? c0v  : (ch == 1) ? c0p  : c0r;

    // bounds per (ch, m)
    float bmax[3], bmin[3];
    bmax[0] = (ch == 0) ? 20.f : (ch == 1) ? 0.2f  : 0.25f;
    bmin[0] = (ch == 0) ? 12.f : (ch == 1) ? -0.2f : -0.25f;
    bmax[1] = (ch == 0) ? 3.f  : 0.25f;
    bmin[1] = (ch == 0) ? -3.f : -0.25f;
    bmax[2] = (ch == 0) ? 3.f  : 0.15f;
    bmin[2] = (ch == 0) ? -3.f : -0.15f;

    // ---- distributed per-unit state: lane l owns component l ----
    float c_l  = c0_p[row * 16 + l];
    float L_l  = lam_p[row * 16 + l] + cin_p[row * 16 + l];
    float pj_l, cq_l;
    const float beq0 = beq_p[row * 2];
    const float beq1 = beq_p[row * 2 + 1];
    float uo[3][8];                    // lane's 8 constraint rows per derivative order

    // ---- init pass: uo, pj0, cq0 from c0 ----
    {
        float cb[16];
#pragma unroll
        for (int k = 0; k < 16; ++k) cb[k] = __shfl(c_l, k, 16);

        float cqd = 0.f;
#pragma unroll
        for (int k = 0; k < 16; ++k) cqd += ata[l][k] * cb[k];
        cq_l = cqd;

        float pjp[16];
#pragma unroll
        for (int j = 0; j < 16; ++j) pjp[j] = 0.f;
#pragma unroll
        for (int m = 0; m < 3; ++m) {
            float un[8], h[8];
#pragma unroll
            for (int k = 0; k < 8; ++k) un[k] = 0.f;
#pragma unroll
            for (int j = 0; j < 16; ++j) {
                float4 p0 = *(const float4*)&Pt[m][j][4*l];
                float4 p1 = *(const float4*)&Pt[m][j][64 + 4*l];
                un[0] += cb[j]*p0.x; un[1] += cb[j]*p0.y; un[2] += cb[j]*p0.z; un[3] += cb[j]*p0.w;
                un[4] += cb[j]*p1.x; un[5] += cb[j]*p1.y; un[6] += cb[j]*p1.z; un[7] += cb[j]*p1.w;
            }
#pragma unroll
            for (int k = 0; k < 8; ++k) {
                float x = un[k] - bmax[m];
                float rvp = fmaxf(x, 0.f);
                float y = un[k] - bmin[m];
                float rvm = fmaxf(-y, 0.f);
                h[k] = rvp - rvm;
                uo[m][k] = un[k];
            }
#pragma unroll
            for (int j = 0; j < 16; ++j) {
                float4 p0 = *(const float4*)&Pt[m][j][4*l];
                float4 p1 = *(const float4*)&Pt[m][j][64 + 4*l];
                pjp[j] += h[0]*p0.x + h[1]*p0.y + h[2]*p0.z + h[3]*p0.w
                        + h[4]*p1.x + h[5]*p1.y + h[6]*p1.z + h[7]*p1.w;
            }
        }
#pragma unroll
        for (int s = 1; s < 16; s <<= 1) {
#pragma unroll
            for (int j = 0; j < 16; ++j) pjp[j] += __shfl_xor(pjp[j], s, 16);
        }
        float pjl = pjp[0];
#pragma unroll
        for (int k = 1; k < 16; ++k) pjl = (l == k) ? pjp[k] : pjl;
        pj_l = pjl;
    }

    // ---- 15 ADMM iterations ----
    for (int t = 0; t < ITERS; ++t) {
        // KKT solve: rhs_k = L_k + cq_k - pj_k (distributed); lane l owns M row l
        float r_l = L_l + cq_l - pj_l;
        float sj = Ml[l][16] * beq0 + Ml[l][17] * beq1;
#pragma unroll
        for (int k = 0; k < 16; ++k) sj += Ml[l][k] * __shfl(r_l, k, 16);

        float d = sj - c_l;
        float cdel2 = d * d;           // per-lane partial of ||c_new - c_old||^2
        c_l = sj;

        // broadcast new c
        float cb[16];
#pragma unroll
        for (int k = 0; k < 16; ++k) cb[k] = __shfl(c_l, k, 16);

        // cq for next solve: lane l computes (AtA c)_l
        float cqd = 0.f;
#pragma unroll
        for (int k = 0; k < 16; ++k) cqd += ata[l][k] * cb[k];
        cq_l = cqd;

        // projection passes
        float res2 = 0.f, ds2 = 0.f;
        float pjp[16];
#pragma unroll
        for (int j = 0; j < 16; ++j) pjp[j] = 0.f;

#pragma unroll
        for (int m = 0; m < 3; ++m) {
            float un[8], h[8];
#pragma unroll
            for (int k = 0; k < 8; ++k) un[k] = 0.f;
#pragma unroll
            for (int j = 0; j < 16; ++j) {
                float4 p0 = *(const float4*)&Pt[m][j][4*l];
                float4 p1 = *(const float4*)&Pt[m][j][64 + 4*l];
                un[0] += cb[j]*p0.x; un[1] += cb[j]*p0.y; un[2] += cb[j]*p0.z; un[3] += cb[j]*p0.w;
                un[4] += cb[j]*p1.x; un[5] += cb[j]*p1.y; un[6] += cb[j]*p1.z; un[7] += cb[j]*p1.w;
            }
#pragma unroll
            for (int k = 0; k < 8; ++k) {
                float x   = un[k] - bmax[m];
                float rvp = fmaxf(x, 0.f);        // relu(Ax - bmax)
                float spn = rvp - x;              // relu(bmax - Ax)  (new s+)
                float y   = un[k] - bmin[m];
                float smn = fmaxf(y, 0.f);        // relu(Ax - bmin)  (new s-)
                float rvm = smn - y;              // relu(bmin - Ax)
                res2 += rvp * rvp;
                res2 += rvm * rvm;
                h[k] = rvp - rvm;
                float xo  = uo[m][k] - bmax[m];
                float spo = fmaxf(-xo, 0.f);      // old s+
                float yo  = uo[m][k] - bmin[m];
                float smo = fmaxf(yo, 0.f);       // old s-
                float e1 = spn - spo;
                float e2 = smn - smo;
                ds2 += e1 * e1;
                ds2 += e2 * e2;
                uo[m][k] = un[k];
            }
#pragma unroll
            for (int j = 0; j < 16; ++j) {
                float4 p0 = *(const float4*)&Pt[m][j][4*l];
                float4 p1 = *(const float4*)&Pt[m][j][64 + 4*l];
                pjp[j] += h[0]*p0.x + h[1]*p0.y + h[2]*p0.z + h[3]*p0.w
                        + h[4]*p1.x + h[5]*p1.y + h[6]*p1.z + h[7]*p1.w;
            }
        }

        // butterfly reduce: pjp[16] + res2 + ds2 + cdel2 across the 16 lanes
#pragma unroll
        for (int s = 1; s < 16; s <<= 1) {
#pragma unroll
            for (int j = 0; j < 16; ++j) pjp[j] += __shfl_xor(pjp[j], s, 16);
            res2  += __shfl_xor(res2,  s, 16);
            ds2   += __shfl_xor(ds2,   s, 16);
            cdel2 += __shfl_xor(cdel2, s, 16);
        }

        // lane l extracts its component (static cndmask chain, no scratch)
        float pjl = pjp[0];
#pragma unroll
        for (int k = 1; k < 16; ++k) pjl = (l == k) ? pjp[k] : pjl;

        // ||lamda_new - lamda_old||^2 = sum pj^2 (replicated: all lanes have full pjp)
        float ln2 = 0.f;
#pragma unroll
        for (int k = 0; k < 16; ++k) ln2 += pjp[k] * pjp[k];

        L_l -= pjl;
        pj_l = pjl;

        if (l == 0) {
            res_st[t][g] = sqrtf(res2);
            fix_st[t][g] = sqrtf(ln2) + sqrtf(ds2) + sqrtf(cdel2);
        }
    }

    // ---- outputs ----
    out[ch * (BATCH * NVARS) + row * 16 + l] = c_l;   // lane l owns c[l]

    __syncthreads();
    const int t2 = threadIdx.x;
    if (t2 < 60) {
        int it = t2 % 15, r2 = t2 / 15, gb = r2 * 3;
        out[OUT_PST + it * BATCH + blockIdx.x * 4 + r2] =
            res_st[it][gb] + res_st[it][gb + 1] + res_st[it][gb + 2];
    } else if (t2 < 120) {
        int t3 = t2 - 60;
        int it = t3 % 15, r2 = t3 / 15, gb = r2 * 3;
        out[OUT_FST + it * BATCH + blockIdx.x * 4 + r2] =
            fix_st[it][gb] + fix_st[it][gb + 1] + fix_st[it][gb + 2];
    } else if (t2 < 124) {
        int r2 = t2 - 120, gb = r2 * 3;
        float s = 0.f;
        for (int it = 0; it < ITERS; ++it)
            s += fix_st[it][gb] + fix_st[it][gb + 1] + fix_st[it][gb + 2];
        out[OUT_ACCF + blockIdx.x * 4 + r2] = s * (1.f / 15.f);
    } else if (t2 < 128) {
        int r2 = t2 - 124, gb = r2 * 3;
        float s = 0.f;
        for (int it = 0; it < ITERS; ++it)
            s += res_st[it][gb] + res_st[it][gb + 1] + res_st[it][gb + 2];
        out[OUT_ACCP + blockIdx.x * 4 + r2] = s * (1.f / 15.f);
    }
}

extern "C" void kernel_launch(void* const* d_in, const int* in_sizes, int n_in,
                              void* d_out, int out_size, void* d_ws, size_t ws_size,
                              hipStream_t stream)
{
    const float* P    = (const float*)d_in[0];
    const float* Pdm  = (const float*)d_in[1];
    const float* Pddm = (const float*)d_in[2];
    const float* lamv = (const float*)d_in[3];
    const float* lamp = (const float*)d_in[4];
    const float* lamr = (const float*)d_in[5];
    const float* cinv = (const float*)d_in[6];
    const float* cinp = (const float*)d_in[7];
    const float* cinr = (const float*)d_in[8];
    const float* beqv = (const float*)d_in[9];
    const float* beqp = (const float*)d_in[10];
    const float* beqr = (const float*)d_in[11];
    const float* c0v  = (const float*)d_in[12];
    const float* c0p  = (const float*)d_in[13];
    const float* c0r  = (const float*)d_in[14];
    float* ws = (float*)d_ws;

    prep_kernel<<<1, 648, 0, stream>>>(P, Pdm, Pddm, ws);
    solve_kernel<<<2048, 192, 0, stream>>>(P, Pdm, Pddm,
        lamv, lamp, lamr, cinv, cinp, cinr,
        beqv, beqp, beqr, c0v, c0p, c0r,
        (float*)d_out, ws);
}

// Round 9
// 653.263 us; speedup vs baseline: 9.2972x; 4.0469x over previous
//
#include <hip/hip_runtime.h>

#define NUMS   128
#define NVARS  16
#define BATCH  8192
#define ITERS  15

// d_out element offsets (return order: cv, cp, cr, acc_fixed, acc_primal, primal_stack, fixed_stack)
#define OUT_ACCF (3*BATCH*NVARS)           // 393216
#define OUT_ACCP (OUT_ACCF + BATCH)        // 401408
#define OUT_PST  (OUT_ACCP + BATCH)        // 409600
#define OUT_FST  (OUT_PST + ITERS*BATCH)   // 532480

// ---------------------------------------------------------------------------
// prep: AtA = 2(P^T P + Pd^T Pd + Pdd^T Pdd); cost_mat = [[I+AtA, Aeq^T],[Aeq,0]];
// M = inv(cost_mat) via f64 Gauss-Jordan. ws: [0,324) M row-major f32,
// [324,596) AtA padded [16][17] f32.
// ---------------------------------------------------------------------------
__global__ void prep_kernel(const float* __restrict__ P, const float* __restrict__ Pd,
                            const float* __restrict__ Pdd, float* __restrict__ ws)
{
    __shared__ double GA[18][36];
    __shared__ float  ata[16][16];
    __shared__ double piv_s;
    const int t = threadIdx.x;

    if (t < 256) {
        int j = t >> 4, k = t & 15;
        float s = 0.f;
        for (int i = 0; i < NUMS; ++i)
            s += P[i*16+j]*P[i*16+k] + Pd[i*16+j]*Pd[i*16+k] + Pdd[i*16+j]*Pdd[i*16+k];
        ata[j][k] = 2.f * s;
    }
    __syncthreads();

    const int gi = t / 36, gj = t % 36;   // blockDim = 648
    {
        double v;
        if (gj < 18) {
            if (gi < 16 && gj < 16)      v = (gi == gj ? 1.0 : 0.0) + (double)ata[gi][gj];
            else if (gi < 16)            v = (gj == 16) ? (double)P[gi] : (double)Pd[gi];
            else if (gj < 16)            v = (gi == 16) ? (double)P[gj] : (double)Pd[gj];
            else                         v = 0.0;
        } else {
            v = ((gj - 18) == gi) ? 1.0 : 0.0;
        }
        GA[gi][gj] = v;
    }
    __syncthreads();

    for (int k = 0; k < 18; ++k) {
        if (t == 0) piv_s = GA[k][k];
        __syncthreads();
        if (gi == k) GA[gi][gj] /= piv_s;
        __syncthreads();
        double f  = GA[gi][k];
        double rk = GA[k][gj];
        __syncthreads();
        if (gi != k) GA[gi][gj] -= f * rk;
        __syncthreads();
    }

    if (gj >= 18) ws[gi*18 + (gj - 18)] = (float)GA[gi][gj];
    if (t < 256)  ws[324 + (t >> 4)*17 + (t & 15)] = ata[t >> 4][t & 15];
    if (t >= 256 && t < 272) ws[324 + (t - 256)*17 + 16] = 0.f;
}

// ---------------------------------------------------------------------------
// main solver: block = 192 threads = 12 groups of 16 lanes = 4 rows x 3 channels.
// R8 lesson: even at the 256 arch-VGPR max, the fully-unrolled two-pass body
// (pjp[16]+cb[16]+butterfly) spilled ~940B/thread. This version routes the
// cross-lane vectors through LDS instead of registers:
//   - c lives in cs[12][16] (broadcast scalar reads in a rolled j-loop)
//   - h is written to hs (per-unit stride 388 = 4 mod 32 banks, separates units)
//   - pj_l = per-lane 384-dot of Pt row l with h, chunk index rotated by lane
//     ((l+t)&31) to break the row-stride-128 bank alias (2-way = free)
// Kills pjp[16], cb[16], and the 76-shuffle butterfly (only 4 scalars remain).
// Live set ~80 regs. #pragma unroll 4 keeps the scheduler from hoist-exploding.
// ---------------------------------------------------------------------------
__launch_bounds__(192, 1)
__global__ void solve_kernel(
    const float* __restrict__ P,    const float* __restrict__ Pd,   const float* __restrict__ Pdd,
    const float* __restrict__ lamv, const float* __restrict__ lamp, const float* __restrict__ lamr,
    const float* __restrict__ cinv, const float* __restrict__ cinp, const float* __restrict__ cinr,
    const float* __restrict__ beqv, const float* __restrict__ beqp, const float* __restrict__ beqr,
    const float* __restrict__ c0v,  const float* __restrict__ c0p,  const float* __restrict__ c0r,
    float* __restrict__ out, const float* __restrict__ ws)
{
    __shared__ __align__(16) float Pt[3][16][128];   // transposed: Pt[m][j][i]
    __shared__ float Ml[16][19];                     // M rows 0..15, cols 0..17 (pad 19)
    __shared__ float ata[16][17];
    __shared__ __align__(16) float hs[12*388];       // per-unit h (3m x 128), stride 388
    __shared__ float cs[12][16];                     // per-unit c
    __shared__ float res_st[ITERS][12];
    __shared__ float fix_st[ITERS][12];

    // ---- stage constants ----
#pragma unroll
    for (int m = 0; m < 3; ++m) {
        const float* src = (m == 0) ? P : (m == 1) ? Pd : Pdd;
        for (int f = threadIdx.x; f < 2048; f += 192) {
            int j = f >> 7, i = f & 127;
            Pt[m][j][i] = src[i*16 + j];
        }
    }
    for (int f = threadIdx.x; f < 288; f += 192) Ml[f / 18][f % 18] = ws[f];
    for (int f = threadIdx.x; f < 272; f += 192) ((float*)ata)[f] = ws[324 + f];
    __syncthreads();

    const int g  = threadIdx.x >> 4;   // group 0..11
    const int l  = threadIdx.x & 15;   // lane-in-group
    const int rl = g / 3;              // local row 0..3
    const int ch = g - rl * 3;         // channel 0..2
    const int row = blockIdx.x * 4 + rl;
    float* hu = &hs[g * 388];

    const float* lam_p = (ch == 0) ? lamv : (ch == 1) ? lamp : lamr;
    const float* cin_p = (ch == 0) ? cinv : (ch == 1) ? cinp : cinr;
    const float* beq_p = (ch == 0) ? beqv : (ch == 1) ? beqp : beqr;
    const float* c0_p  = (ch == 0) ? c0v  : (ch == 1) ? c0p  : c0r;

    // bounds per (ch, m)
    float bmax[3], bmin[3];
    bmax[0] = (ch == 0) ? 20.f : (ch == 1) ? 0.2f  : 0.25f;
    bmin[0] = (ch == 0) ? 12.f : (ch == 1) ? -0.2f : -0.25f;
    bmax[1] = (ch == 0) ? 3.f  : 0.25f;
    bmin[1] = (ch == 0) ? -3.f : -0.25f;
    bmax[2] = (ch == 0) ? 3.f  : 0.15f;
    bmin[2] = (ch == 0) ? -3.f : -0.15f;

    // ---- distributed per-unit state: lane l owns component l ----
    float c_l  = c0_p[row * 16 + l];
    float L_l  = lam_p[row * 16 + l] + cin_p[row * 16 + l];
    float pj_l, cq_l;
    const float beq0 = beq_p[row * 2];
    const float beq1 = beq_p[row * 2 + 1];
    float uo[3][8];                    // lane's 8 constraint rows per derivative order

    cs[g][l] = c_l;

    // ---- init pass: uo, h0 -> hs, cq0, pj0 ----
    {
#pragma unroll
        for (int m = 0; m < 3; ++m) {
            float un[8];
#pragma unroll
            for (int k = 0; k < 8; ++k) un[k] = 0.f;
#pragma unroll 4
            for (int j = 0; j < 16; ++j) {
                float cj = cs[g][j];
                float4 p0 = *(const float4*)&Pt[m][j][4*l];
                float4 p1 = *(const float4*)&Pt[m][j][64 + 4*l];
                un[0] += cj*p0.x; un[1] += cj*p0.y; un[2] += cj*p0.z; un[3] += cj*p0.w;
                un[4] += cj*p1.x; un[5] += cj*p1.y; un[6] += cj*p1.z; un[7] += cj*p1.w;
            }
            float h[8];
#pragma unroll
            for (int k = 0; k < 8; ++k) {
                float x = un[k] - bmax[m];
                float rvp = fmaxf(x, 0.f);
                float y = un[k] - bmin[m];
                float rvm = fmaxf(-y, 0.f);
                h[k] = rvp - rvm;
                uo[m][k] = un[k];
            }
            *(float4*)&hu[m*128 + 4*l]      = make_float4(h[0], h[1], h[2], h[3]);
            *(float4*)&hu[m*128 + 64 + 4*l] = make_float4(h[4], h[5], h[6], h[7]);
        }
        float cqd = 0.f;
#pragma unroll
        for (int k = 0; k < 16; ++k) cqd += ata[l][k] * cs[g][k];
        cq_l = cqd;

        float pjd = 0.f;
#pragma unroll
        for (int m = 0; m < 3; ++m) {
            const float* ptl = &Pt[m][l][0];
            const float* hm  = &hu[m*128];
#pragma unroll 4
            for (int t = 0; t < 32; ++t) {
                int ci = ((l + t) & 31) * 4;
                float4 p  = *(const float4*)(ptl + ci);
                float4 hv = *(const float4*)(hm + ci);
                pjd += p.x*hv.x + p.y*hv.y + p.z*hv.z + p.w*hv.w;
            }
        }
        pj_l = pjd;
    }

    // ---- 15 ADMM iterations ----
    for (int t = 0; t < ITERS; ++t) {
        // KKT solve: rhs_k = L_k + cq_k - pj_k; lane l owns M row l
        float r_l = L_l + cq_l - pj_l;
        float sj = Ml[l][16] * beq0 + Ml[l][17] * beq1;
#pragma unroll
        for (int k = 0; k < 16; ++k) sj += Ml[l][k] * __shfl(r_l, k, 16);

        float d = sj - c_l;
        float cdel2 = d * d;
        c_l = sj;
        cs[g][l] = c_l;

        // Ax + projection pass (writes h to hs)
        float res2 = 0.f, ds2 = 0.f;
#pragma unroll
        for (int m = 0; m < 3; ++m) {
            float un[8];
#pragma unroll
            for (int k = 0; k < 8; ++k) un[k] = 0.f;
#pragma unroll 4
            for (int j = 0; j < 16; ++j) {
                float cj = cs[g][j];
                float4 p0 = *(const float4*)&Pt[m][j][4*l];
                float4 p1 = *(const float4*)&Pt[m][j][64 + 4*l];
                un[0] += cj*p0.x; un[1] += cj*p0.y; un[2] += cj*p0.z; un[3] += cj*p0.w;
                un[4] += cj*p1.x; un[5] += cj*p1.y; un[6] += cj*p1.z; un[7] += cj*p1.w;
            }
            float h[8];
#pragma unroll
            for (int k = 0; k < 8; ++k) {
                float x   = un[k] - bmax[m];
                float rvp = fmaxf(x, 0.f);        // relu(Ax - bmax)
                float spn = rvp - x;              // new s+
                float y   = un[k] - bmin[m];
                float smn = fmaxf(y, 0.f);        // new s-
                float rvm = smn - y;              // relu(bmin - Ax)
                res2 += rvp * rvp + rvm * rvm;
                h[k] = rvp - rvm;
                float xo  = uo[m][k] - bmax[m];
                float spo = fmaxf(-xo, 0.f);      // old s+
                float yo  = uo[m][k] - bmin[m];
                float smo = fmaxf(yo, 0.f);       // old s-
                float e1 = spn - spo;
                float e2 = smn - smo;
                ds2 += e1 * e1 + e2 * e2;
                uo[m][k] = un[k];
            }
            *(float4*)&hu[m*128 + 4*l]      = make_float4(h[0], h[1], h[2], h[3]);
            *(float4*)&hu[m*128 + 64 + 4*l] = make_float4(h[4], h[5], h[6], h[7]);
        }

        // cq for next solve
        float cqd = 0.f;
#pragma unroll
        for (int k = 0; k < 16; ++k) cqd += ata[l][k] * cs[g][k];
        cq_l = cqd;

        // pj pass: lane l computes (A^T h)_l as a 384-dot, lane-rotated chunks
        float pjd = 0.f;
#pragma unroll
        for (int m = 0; m < 3; ++m) {
            const float* ptl = &Pt[m][l][0];
            const float* hm  = &hu[m*128];
#pragma unroll 4
            for (int t2 = 0; t2 < 32; ++t2) {
                int ci = ((l + t2) & 31) * 4;
                float4 p  = *(const float4*)(ptl + ci);
                float4 hv = *(const float4*)(hm + ci);
                pjd += p.x*hv.x + p.y*hv.y + p.z*hv.z + p.w*hv.w;
            }
        }
        pj_l = pjd;
        float pj2 = pj_l * pj_l;

        // butterfly 4 scalars across the 16 lanes
#pragma unroll
        for (int s = 1; s < 16; s <<= 1) {
            res2  += __shfl_xor(res2,  s, 16);
            ds2   += __shfl_xor(ds2,   s, 16);
            cdel2 += __shfl_xor(cdel2, s, 16);
            pj2   += __shfl_xor(pj2,   s, 16);
        }

        L_l -= pj_l;

        if (l == 0) {
            res_st[t][g] = sqrtf(res2);
            fix_st[t][g] = sqrtf(pj2) + sqrtf(ds2) + sqrtf(cdel2);
        }
    }

    // ---- outputs ----
    out[ch * (BATCH * NVARS) + row * 16 + l] = c_l;   // lane l owns c[l]

    __syncthreads();
    const int t2 = threadIdx.x;
    if (t2 < 60) {
        int it = t2 % 15, r2 = t2 / 15, gb = r2 * 3;
        out[OUT_PST + it * BATCH + blockIdx.x * 4 + r2] =
            res_st[it][gb] + res_st[it][gb + 1] + res_st[it][gb + 2];
    } else if (t2 < 120) {
        int t3 = t2 - 60;
        int it = t3 % 15, r2 = t3 / 15, gb = r2 * 3;
        out[OUT_FST + it * BATCH + blockIdx.x * 4 + r2] =
            fix_st[it][gb] + fix_st[it][gb + 1] + fix_st[it][gb + 2];
    } else if (t2 < 124) {
        int r2 = t2 - 120, gb = r2 * 3;
        float s = 0.f;
        for (int it = 0; it < ITERS; ++it)
            s += fix_st[it][gb] + fix_st[it][gb + 1] + fix_st[it][gb + 2];
        out[OUT_ACCF + blockIdx.x * 4 + r2] = s * (1.f / 15.f);
    } else if (t2 < 128) {
        int r2 = t2 - 124, gb = r2 * 3;
        float s = 0.f;
        for (int it = 0; it < ITERS; ++it)
            s += res_st[it][gb] + res_st[it][gb + 1] + res_st[it][gb + 2];
        out[OUT_ACCP + blockIdx.x * 4 + r2] = s * (1.f / 15.f);
    }
}

extern "C" void kernel_launch(void* const* d_in, const int* in_sizes, int n_in,
                              void* d_out, int out_size, void* d_ws, size_t ws_size,
                              hipStream_t stream)
{
    const float* P    = (const float*)d_in[0];
    const float* Pdm  = (const float*)d_in[1];
    const float* Pddm = (const float*)d_in[2];
    const float* lamv = (const float*)d_in[3];
    const float* lamp = (const float*)d_in[4];
    const float* lamr = (const float*)d_in[5];
    const float* cinv = (const float*)d_in[6];
    const float* cinp = (const float*)d_in[7];
    const float* cinr = (const float*)d_in[8];
    const float* beqv = (const float*)d_in[9];
    const float* beqp = (const float*)d_in[10];
    const float* beqr = (const float*)d_in[11];
    const float* c0v  = (const float*)d_in[12];
    const float* c0p  = (const float*)d_in[13];
    const float* c0r  = (const float*)d_in[14];
    float* ws = (float*)d_ws;

    prep_kernel<<<1, 648, 0, stream>>>(P, Pdm, Pddm, ws);
    solve_kernel<<<2048, 192, 0, stream>>>(P, Pdm, Pddm,
        lamv, lamp, lamr, cinv, cinp, cinr,
        beqv, beqp, beqr, c0v, c0p, c0r,
        (float*)d_out, ws);
}

// Round 11
// 454.650 us; speedup vs baseline: 13.3587x; 1.4368x over previous
//
#include <hip/hip_runtime.h>

#define NUMS   128
#define NVARS  16
#define BATCH  8192
#define ITERS  15

// d_out element offsets (return order: cv, cp, cr, acc_fixed, acc_primal, primal_stack, fixed_stack)
#define OUT_ACCF (3*BATCH*NVARS)           // 393216
#define OUT_ACCP (OUT_ACCF + BATCH)        // 401408
#define OUT_PST  (OUT_ACCP + BATCH)        // 409600
#define OUT_FST  (OUT_PST + ITERS*BATCH)   // 532480

// ---------------------------------------------------------------------------
// prep: AtA = 2(P^T P + Pd^T Pd + Pdd^T Pdd); cost_mat = [[I+AtA, Aeq^T],[Aeq,0]];
// M = inv(cost_mat) via f64 Gauss-Jordan. ws: [0,324) M row-major f32,
// [324,596) AtA padded [16][17] f32.
// ---------------------------------------------------------------------------
__global__ void prep_kernel(const float* __restrict__ P, const float* __restrict__ Pd,
                            const float* __restrict__ Pdd, float* __restrict__ ws)
{
    __shared__ double GA[18][36];
    __shared__ float  ata[16][16];
    __shared__ double piv_s;
    const int t = threadIdx.x;

    if (t < 256) {
        int j = t >> 4, k = t & 15;
        float s = 0.f;
        for (int i = 0; i < NUMS; ++i)
            s += P[i*16+j]*P[i*16+k] + Pd[i*16+j]*Pd[i*16+k] + Pdd[i*16+j]*Pdd[i*16+k];
        ata[j][k] = 2.f * s;
    }
    __syncthreads();

    const int gi = t / 36, gj = t % 36;   // blockDim = 648
    {
        double v;
        if (gj < 18) {
            if (gi < 16 && gj < 16)      v = (gi == gj ? 1.0 : 0.0) + (double)ata[gi][gj];
            else if (gi < 16)            v = (gj == 16) ? (double)P[gi] : (double)Pd[gi];
            else if (gj < 16)            v = (gi == 16) ? (double)P[gj] : (double)Pd[gj];
            else                         v = 0.0;
        } else {
            v = ((gj - 18) == gi) ? 1.0 : 0.0;
        }
        GA[gi][gj] = v;
    }
    __syncthreads();

    for (int k = 0; k < 18; ++k) {
        if (t == 0) piv_s = GA[k][k];
        __syncthreads();
        if (gi == k) GA[gi][gj] /= piv_s;
        __syncthreads();
        double f  = GA[gi][k];
        double rk = GA[k][gj];
        __syncthreads();
        if (gi != k) GA[gi][gj] -= f * rk;
        __syncthreads();
    }

    if (gj >= 18) ws[gi*18 + (gj - 18)] = (float)GA[gi][gj];
    if (t < 256)  ws[324 + (t >> 4)*17 + (t & 15)] = ata[t >> 4][t & 15];
    if (t >= 256 && t < 272) ws[324 + (t - 256)*17 + 16] = 0.f;
}

// ---------------------------------------------------------------------------
// main solver: block = 192 threads = 12 groups of 16 lanes = 4 rows x 3 channels.
// R9 lesson: h-through-LDS pj pass was 8-way bank-conflicted (3.78e7 conflict
// cycles) + 96 extra b128/lane/iter. This version keeps h[8] in registers and
// accumulates pjp[16] reading the SAME broadcast-free Pt addresses as the Ax
// pass (4 groups/wave read identical addrs = free), then REDUCE-SCATTERS pjp
// across the 16 lanes (4 halving stages, static cndmask indexing, 15 shfl)
// so lane l ends with exactly pj_l. No hs buffer -> LDS ~29KB, 5 blocks/CU.
// ---------------------------------------------------------------------------
__launch_bounds__(192, 1)
__global__ void solve_kernel(
    const float* __restrict__ P,    const float* __restrict__ Pd,   const float* __restrict__ Pdd,
    const float* __restrict__ lamv, const float* __restrict__ lamp, const float* __restrict__ lamr,
    const float* __restrict__ cinv, const float* __restrict__ cinp, const float* __restrict__ cinr,
    const float* __restrict__ beqv, const float* __restrict__ beqp, const float* __restrict__ beqr,
    const float* __restrict__ c0v,  const float* __restrict__ c0p,  const float* __restrict__ c0r,
    float* __restrict__ out, const float* __restrict__ ws)
{
    __shared__ __align__(16) float Pt[3][16][128];   // transposed: Pt[m][j][i]
    __shared__ float Ml[16][19];                     // M rows 0..15, cols 0..17 (pad 19)
    __shared__ float ata[16][17];
    __shared__ float cs[12][16];                     // per-unit c (group-local broadcast)
    __shared__ float res_st[ITERS][12];
    __shared__ float fix_st[ITERS][12];

    // ---- stage constants ----
#pragma unroll
    for (int m = 0; m < 3; ++m) {
        const float* src = (m == 0) ? P : (m == 1) ? Pd : Pdd;
        for (int f = threadIdx.x; f < 2048; f += 192) {
            int j = f >> 7, i = f & 127;
            Pt[m][j][i] = src[i*16 + j];
        }
    }
    for (int f = threadIdx.x; f < 288; f += 192) Ml[f / 18][f % 18] = ws[f];
    for (int f = threadIdx.x; f < 272; f += 192) ((float*)ata)[f] = ws[324 + f];
    __syncthreads();

    const int g  = threadIdx.x >> 4;   // group 0..11
    const int l  = threadIdx.x & 15;   // lane-in-group
    const int rl = g / 3;              // local row 0..3
    const int ch = g - rl * 3;         // channel 0..2
    const int row = blockIdx.x * 4 + rl;

    const float* lam_p = (ch == 0) ? lamv : (ch == 1) ? lamp : lamr;
    const float* cin_p = (ch == 0) ? cinv : (ch == 1) ? cinp : cinr;
    const float* beq_p = (ch == 0) ? beqv : (ch == 1) ? beqp : beqr;
    const float* c0_p  = (ch == 0) ? c0v  : (ch == 1) ? c0p  : c0r;

    // bounds per (ch, m)
    float bmax[3], bmin[3];
    bmax[0] = (ch == 0) ? 20.f : (ch == 1) ? 0.2f  : 0.25f;
    bmin[0] = (ch == 0) ? 12.f : (ch == 1) ? -0.2f : -0.25f;
    bmax[1] = (ch == 0) ? 3.f  : 0.25f;
    bmin[1] = (ch == 0) ? -3.f : -0.25f;
    bmax[2] = (ch == 0) ? 3.f  : 0.15f;
    bmin[2] = (ch == 0) ? -3.f : -0.15f;

    // ---- distributed per-unit state: lane l owns component l ----
    float c_l  = c0_p[row * 16 + l];
    float L_l  = lam_p[row * 16 + l] + cin_p[row * 16 + l];
    float pj_l, cq_l;
    const float beq0 = beq_p[row * 2];
    const float beq1 = beq_p[row * 2 + 1];
    float uo[3][8];                    // lane's 8 constraint rows per derivative order

    cs[g][l] = c_l;

    // ---- init pass: uo, pjp0 -> reduce-scatter -> pj_l; cq0 ----
    {
        float pjp[16];
#pragma unroll
        for (int j = 0; j < 16; ++j) pjp[j] = 0.f;

#pragma unroll
        for (int m = 0; m < 3; ++m) {
            float un[8];
#pragma unroll
            for (int k = 0; k < 8; ++k) un[k] = 0.f;
#pragma unroll 4
            for (int j = 0; j < 16; ++j) {
                float cj = cs[g][j];
                float4 p0 = *(const float4*)&Pt[m][j][4*l];
                float4 p1 = *(const float4*)&Pt[m][j][64 + 4*l];
                un[0] += cj*p0.x; un[1] += cj*p0.y; un[2] += cj*p0.z; un[3] += cj*p0.w;
                un[4] += cj*p1.x; un[5] += cj*p1.y; un[6] += cj*p1.z; un[7] += cj*p1.w;
            }
            float h[8];
#pragma unroll
            for (int k = 0; k < 8; ++k) {
                float x = un[k] - bmax[m];
                float rvp = fmaxf(x, 0.f);
                float y = un[k] - bmin[m];
                float rvm = fmaxf(-y, 0.f);
                h[k] = rvp - rvm;
                uo[m][k] = un[k];
            }
#pragma unroll 4
            for (int j = 0; j < 16; ++j) {
                float4 p0 = *(const float4*)&Pt[m][j][4*l];
                float4 p1 = *(const float4*)&Pt[m][j][64 + 4*l];
                pjp[j] += h[0]*p0.x + h[1]*p0.y + h[2]*p0.z + h[3]*p0.w
                        + h[4]*p1.x + h[5]*p1.y + h[6]*p1.z + h[7]*p1.w;
            }
        }

        // reduce-scatter pjp[16] -> lane l holds sum for j = l
        float v8[8];
#pragma unroll
        for (int k = 0; k < 8; ++k) {
            float send = (l & 8) ? pjp[k] : pjp[k+8];
            float keep = (l & 8) ? pjp[k+8] : pjp[k];
            v8[k] = keep + __shfl_xor(send, 8, 16);
        }
        float v4[4];
#pragma unroll
        for (int k = 0; k < 4; ++k) {
            float send = (l & 4) ? v8[k] : v8[k+4];
            float keep = (l & 4) ? v8[k+4] : v8[k];
            v4[k] = keep + __shfl_xor(send, 4, 16);
        }
        float v2[2];
#pragma unroll
        for (int k = 0; k < 2; ++k) {
            float send = (l & 2) ? v4[k] : v4[k+2];
            float keep = (l & 2) ? v4[k+2] : v4[k];
            v2[k] = keep + __shfl_xor(send, 2, 16);
        }
        {
            float send = (l & 1) ? v2[0] : v2[1];
            float keep = (l & 1) ? v2[1] : v2[0];
            pj_l = keep + __shfl_xor(send, 1, 16);
        }

        float cqd = 0.f;
#pragma unroll
        for (int k = 0; k < 16; ++k) cqd += ata[l][k] * cs[g][k];
        cq_l = cqd;
    }

    // ---- 15 ADMM iterations ----
    for (int t = 0; t < ITERS; ++t) {
        // KKT solve: rhs_k = L_k + cq_k - pj_k; lane l owns M row l
        float r_l = L_l + cq_l - pj_l;
        float sj = Ml[l][16] * beq0 + Ml[l][17] * beq1;
#pragma unroll
        for (int k = 0; k < 16; ++k) sj += Ml[l][k] * __shfl(r_l, k, 16);

        float d = sj - c_l;
        float cdel2 = d * d;
        c_l = sj;
        cs[g][l] = c_l;

        // fused Ax + projection + pjp accumulation (h stays in registers)
        float res2 = 0.f, ds2 = 0.f;
        float pjp[16];
#pragma unroll
        for (int j = 0; j < 16; ++j) pjp[j] = 0.f;

#pragma unroll
        for (int m = 0; m < 3; ++m) {
            float un[8];
#pragma unroll
            for (int k = 0; k < 8; ++k) un[k] = 0.f;
#pragma unroll 4
            for (int j = 0; j < 16; ++j) {
                float cj = cs[g][j];
                float4 p0 = *(const float4*)&Pt[m][j][4*l];
                float4 p1 = *(const float4*)&Pt[m][j][64 + 4*l];
                un[0] += cj*p0.x; un[1] += cj*p0.y; un[2] += cj*p0.z; un[3] += cj*p0.w;
                un[4] += cj*p1.x; un[5] += cj*p1.y; un[6] += cj*p1.z; un[7] += cj*p1.w;
            }
            float h[8];
#pragma unroll
            for (int k = 0; k < 8; ++k) {
                float x   = un[k] - bmax[m];
                float rvp = fmaxf(x, 0.f);        // relu(Ax - bmax)
                float spn = rvp - x;              // new s+
                float y   = un[k] - bmin[m];
                float smn = fmaxf(y, 0.f);        // new s-
                float rvm = smn - y;              // relu(bmin - Ax)
                res2 += rvp * rvp + rvm * rvm;
                h[k] = rvp - rvm;
                float xo  = uo[m][k] - bmax[m];
                float spo = fmaxf(-xo, 0.f);      // old s+
                float yo  = uo[m][k] - bmin[m];
                float smo = fmaxf(yo, 0.f);       // old s-
                float e1 = spn - spo;
                float e2 = smn - smo;
                ds2 += e1 * e1 + e2 * e2;
                uo[m][k] = un[k];
            }
#pragma unroll 4
            for (int j = 0; j < 16; ++j) {
                float4 p0 = *(const float4*)&Pt[m][j][4*l];
                float4 p1 = *(const float4*)&Pt[m][j][64 + 4*l];
                pjp[j] += h[0]*p0.x + h[1]*p0.y + h[2]*p0.z + h[3]*p0.w
                        + h[4]*p1.x + h[5]*p1.y + h[6]*p1.z + h[7]*p1.w;
            }
        }

        // reduce-scatter pjp[16] -> pj_l (4 halving stages, 15 shfl)
        float v8[8];
#pragma unroll
        for (int k = 0; k < 8; ++k) {
            float send = (l & 8) ? pjp[k] : pjp[k+8];
            float keep = (l & 8) ? pjp[k+8] : pjp[k];
            v8[k] = keep + __shfl_xor(send, 8, 16);
        }
        float v4[4];
#pragma unroll
        for (int k = 0; k < 4; ++k) {
            float send = (l & 4) ? v8[k] : v8[k+4];
            float keep = (l & 4) ? v8[k+4] : v8[k];
            v4[k] = keep + __shfl_xor(send, 4, 16);
        }
        float v2[2];
#pragma unroll
        for (int k = 0; k < 2; ++k) {
            float send = (l & 2) ? v4[k] : v4[k+2];
            float keep = (l & 2) ? v4[k+2] : v4[k];
            v2[k] = keep + __shfl_xor(send, 2, 16);
        }
        {
            float send = (l & 1) ? v2[0] : v2[1];
            float keep = (l & 1) ? v2[1] : v2[0];
            pj_l = keep + __shfl_xor(send, 1, 16);
        }

        // cq for next solve
        float cqd = 0.f;
#pragma unroll
        for (int k = 0; k < 16; ++k) cqd += ata[l][k] * cs[g][k];
        cq_l = cqd;

        // butterfly 4 scalars across the 16 lanes (pj2 gives ||lam_new-lam_old||^2)
        float pj2 = pj_l * pj_l;
#pragma unroll
        for (int s = 1; s < 16; s <<= 1) {
            res2  += __shfl_xor(res2,  s, 16);
            ds2   += __shfl_xor(ds2,   s, 16);
            cdel2 += __shfl_xor(cdel2, s, 16);
            pj2   += __shfl_xor(pj2,   s, 16);
        }

        L_l -= pj_l;

        if (l == 0) {
            res_st[t][g] = sqrtf(res2);
            fix_st[t][g] = sqrtf(pj2) + sqrtf(ds2) + sqrtf(cdel2);
        }
    }

    // ---- outputs ----
    out[ch * (BATCH * NVARS) + row * 16 + l] = c_l;   // lane l owns c[l]

    __syncthreads();
    const int t2 = threadIdx.x;
    if (t2 < 60) {
        int it = t2 % 15, r2 = t2 / 15, gb = r2 * 3;
        out[OUT_PST + it * BATCH + blockIdx.x * 4 + r2] =
            res_st[it][gb] + res_st[it][gb + 1] + res_st[it][gb + 2];
    } else if (t2 < 120) {
        int t3 = t2 - 60;
        int it = t3 % 15, r2 = t3 / 15, gb = r2 * 3;
        out[OUT_FST + it * BATCH + blockIdx.x * 4 + r2] =
            fix_st[it][gb] + fix_st[it][gb + 1] + fix_st[it][gb + 2];
    } else if (t2 < 124) {
        int r2 = t2 - 120, gb = r2 * 3;
        float s = 0.f;
        for (int it = 0; it < ITERS; ++it)
            s += fix_st[it][gb] + fix_st[it][gb + 1] + fix_st[it][gb + 2];
        out[OUT_ACCF + blockIdx.x * 4 + r2] = s * (1.f / 15.f);
    } else if (t2 < 128) {
        int r2 = t2 - 124, gb = r2 * 3;
        float s = 0.f;
        for (int it = 0; it < ITERS; ++it)
            s += res_st[it][gb] + res_st[it][gb + 1] + res_st[it][gb + 2];
        out[OUT_ACCP + blockIdx.x * 4 + r2] = s * (1.f / 15.f);
    }
}

extern "C" void kernel_launch(void* const* d_in, const int* in_sizes, int n_in,
                              void* d_out, int out_size, void* d_ws, size_t ws_size,
                              hipStream_t stream)
{
    const float* P    = (const float*)d_in[0];
    const float* Pdm  = (const float*)d_in[1];
    const float* Pddm = (const float*)d_in[2];
    const float* lamv = (const float*)d_in[3];
    const float* lamp = (const float*)d_in[4];
    const float* lamr = (const float*)d_in[5];
    const float* cinv = (const float*)d_in[6];
    const float* cinp = (const float*)d_in[7];
    const float* cinr = (const float*)d_in[8];
    const float* beqv = (const float*)d_in[9];
    const float* beqp = (const float*)d_in[10];
    const float* beqr = (const float*)d_in[11];
    const float* c0v  = (const float*)d_in[12];
    const float* c0p  = (const float*)d_in[13];
    const float* c0r  = (const float*)d_in[14];
    float* ws = (float*)d_ws;

    prep_kernel<<<1, 648, 0, stream>>>(P, Pdm, Pddm, ws);
    solve_kernel<<<2048, 192, 0, stream>>>(P, Pdm, Pddm,
        lamv, lamp, lamr, cinv, cinp, cinr,
        beqv, beqp, beqr, c0v, c0p, c0r,
        (float*)d_out, ws);
}